// Round 4
// baseline (121.990 us; speedup 1.0000x reference)
//
#include <hip/hip_runtime.h>
#include <stdint.h>

// Problem geometry (reference: 128^3 grid, padded to 130^3, cells = 129^3)
constexpr int DIM    = 128;
constexpr int NCX    = 129;
constexpr int NCELLS = NCX * NCX * NCX;            // 2,146,689
constexpr size_t NV_ELEMS = (size_t)NCELLS * 12;   // verts region: 25,760,268 f32
constexpr size_t NT_ELEMS = (size_t)NCELLS * 6;    // tris  region: 12,880,134 f32
// vmask region: NCELLS*4 = 8,586,756 f32 ; total = 47,227,158 f32 elements

// clang native vector types (accepted by __builtin_nontemporal_*)
typedef float vf4 __attribute__((ext_vector_type(4)));
typedef float vf2 __attribute__((ext_vector_type(2)));

__global__ __launch_bounds__(256) void mc_kernel(
    const float* __restrict__ grid,
    const float* __restrict__ deform,
    float*       __restrict__ out)
{
    int tid = blockIdx.x * blockDim.x + threadIdx.x;
    if (tid >= NCELLS) return;

    // cell coords, z fastest (reference meshgrid 'ij' + C-order reshape)
    int z = tid % NCX;
    int t = tid / NCX;
    int y = t % NCX;
    int x = t / NCX;

    // 8 cube corners of padded grid gp[x..x+1][y..y+1][z..z+1];
    // gp[i]=grid[i-1] for i in [1,128], else padding value 1.0 (> isovalue 0)
    // Grid has 8x reuse -> plain (caching) loads, keep it L2-resident.
    float cmin = 3.4e38f, cmax = -3.4e38f;
    #pragma unroll
    for (int dx = 0; dx < 2; ++dx) {
        int i = x + dx - 1;
        bool iok = (unsigned)i < (unsigned)DIM;
        #pragma unroll
        for (int dy = 0; dy < 2; ++dy) {
            int j = y + dy - 1;
            bool jok = (unsigned)j < (unsigned)DIM;
            #pragma unroll
            for (int dz = 0; dz < 2; ++dz) {
                int k = z + dz - 1;
                bool kok = (unsigned)k < (unsigned)DIM;
                float v = 1.0f;
                if (iok && jok && kok)
                    v = grid[((size_t)i * DIM + j) * DIM + k];
                cmin = fminf(cmin, v);
                cmax = fmaxf(cmax, v);
            }
        }
    }
    bool active = (cmin <= 0.0f) && (cmax >= 0.0f);
    float m = active ? 1.0f : 0.0f;

    // deform at padded index (x,y,z): zero in padding region.
    // Read exactly once -> nontemporal loads (don't evict grid from L2).
    float d0 = 0.f, d1 = 0.f, d2 = 0.f;
    {
        int i = x - 1, j = y - 1, k = z - 1;
        if ((unsigned)i < (unsigned)DIM && (unsigned)j < (unsigned)DIM &&
            (unsigned)k < (unsigned)DIM) {
            const float* b = deform + (((size_t)i * DIM + j) * DIM + k) * 3;
            d0 = __builtin_nontemporal_load(b);
            d1 = __builtin_nontemporal_load(b + 1);
            d2 = __builtin_nontemporal_load(b + 2);
        }
    }
    float cx = (float)x + 0.5f + d0;
    float cy = (float)y + 0.5f + d1;
    float cz = (float)z + 0.5f + d2;

    // post-transform: (v - 1)/128 - 1  ==  v*(1/128) + (-(1/128) - 1)
    constexpr float S = 1.0f / 128.0f;
    constexpr float B = -(1.0f / 128.0f) - 1.0f;
    float ax = fmaf(cx - 0.3f, S, B) * m;   // quad half-extent OFFSET = 0.3
    float bx = fmaf(cx + 0.3f, S, B) * m;
    float ay = fmaf(cy - 0.3f, S, B) * m;
    float by = fmaf(cy + 0.3f, S, B) * m;
    float gz = fmaf(cz,        S, B) * m;

    // All outputs are write-once streams -> nontemporal (evict-first) stores.

    // --- verts: 12 f32 at out[tid*12] (stride 48 B, 16B-aligned)
    // order: (ax,ay,gz)(bx,ay,gz)(bx,by,gz)(ax,by,gz)
    vf4* pv = reinterpret_cast<vf4*>(out + (size_t)tid * 12);
    __builtin_nontemporal_store((vf4){ax, ay, gz, bx}, pv + 0);
    __builtin_nontemporal_store((vf4){ay, gz, bx, by}, pv + 1);
    __builtin_nontemporal_store((vf4){gz, ax, by, gz}, pv + 2);

    // --- tris: 6 f32 at out[NV + tid*6] = (4*cell + {0,1,2,0,2,3}) * mask
    float c4 = (float)(tid * 4);            // <= 8,586,752 : exact in f32
    vf2* pt = reinterpret_cast<vf2*>(out + NV_ELEMS + (size_t)tid * 6);
    __builtin_nontemporal_store((vf2){c4 * m,          (c4 + 1.0f) * m}, pt + 0);
    __builtin_nontemporal_store((vf2){(c4 + 2.0f) * m,  c4 * m},         pt + 1);
    __builtin_nontemporal_store((vf2){(c4 + 2.0f) * m, (c4 + 3.0f) * m}, pt + 2);

    // --- vmask: 4 identical f32 at out[NV+NT + tid*4] (base 8-mod-16 aligned -> vf2)
    vf2* pm = reinterpret_cast<vf2*>(out + NV_ELEMS + NT_ELEMS + (size_t)tid * 4);
    __builtin_nontemporal_store((vf2){m, m}, pm + 0);
    __builtin_nontemporal_store((vf2){m, m}, pm + 1);
}

extern "C" void kernel_launch(void* const* d_in, const int* in_sizes, int n_in,
                              void* d_out, int out_size, void* d_ws, size_t ws_size,
                              hipStream_t stream) {
    const float* grid   = (const float*)d_in[0];   // [128,128,128] f32
    const float* deform = (const float*)d_in[1];   // [128,128,128,3] f32
    float* out = (float*)d_out;                    // [verts | tris | vmask] f32 concat

    int blocks = (NCELLS + 255) / 256;
    mc_kernel<<<blocks, 256, 0, stream>>>(grid, deform, out);
}

// Round 5
// 39.823 us; speedup vs baseline: 3.0633x; 3.0633x over previous
//
#include <hip/hip_runtime.h>
#include <stdint.h>

// Problem geometry (reference: 128^3 grid, padded to 130^3, cells = 129^3)
constexpr int DIM    = 128;
constexpr int NCX    = 129;
constexpr int NCELLS = NCX * NCX * NCX;            // 2,146,689
constexpr size_t NV_ELEMS = (size_t)NCELLS * 12;   // verts region: 25,760,268 f32
constexpr size_t NT_ELEMS = (size_t)NCELLS * 6;    // tris  region: 12,880,134 f32
// vmask region: NCELLS*4 = 8,586,756 f32 ; total = 47,227,158 f32 elements

constexpr int BLK = 256;

__global__ __launch_bounds__(BLK) void mc_kernel(
    const float* __restrict__ grid,
    const float* __restrict__ deform,
    float*       __restrict__ out)
{
    // LDS staging: per-block output tile, written scatter (conflict-free
    // strides: 48B/24B/16B all tile the 32 banks exactly), read contiguous.
    __shared__ __align__(16) float sv[BLK * 12];   // verts  12,288 B
    __shared__ __align__(16) float st[BLK * 6];    // tris    6,144 B
    __shared__ __align__(16) float sm[BLK * 4];    // vmask   4,096 B

    const int t  = threadIdx.x;
    const int c0 = blockIdx.x * BLK;
    const int cell = c0 + t;

    if (cell < NCELLS) {
        // cell coords, z fastest (reference meshgrid 'ij' + C-order reshape)
        int z = cell % NCX;
        int tt = cell / NCX;
        int y = tt % NCX;
        int x = tt / NCX;

        // 8 cube corners of padded grid; padding value 1.0 (> isovalue 0)
        float cmin = 3.4e38f, cmax = -3.4e38f;
        #pragma unroll
        for (int dx = 0; dx < 2; ++dx) {
            int i = x + dx - 1;
            bool iok = (unsigned)i < (unsigned)DIM;
            #pragma unroll
            for (int dy = 0; dy < 2; ++dy) {
                int j = y + dy - 1;
                bool jok = (unsigned)j < (unsigned)DIM;
                #pragma unroll
                for (int dz = 0; dz < 2; ++dz) {
                    int k = z + dz - 1;
                    bool kok = (unsigned)k < (unsigned)DIM;
                    float v = 1.0f;
                    if (iok && jok && kok)
                        v = grid[((size_t)i * DIM + j) * DIM + k];
                    cmin = fminf(cmin, v);
                    cmax = fmaxf(cmax, v);
                }
            }
        }
        bool active = (cmin <= 0.0f) && (cmax >= 0.0f);
        float m = active ? 1.0f : 0.0f;

        // deform at padded index (x,y,z): zero in padding region
        float d0 = 0.f, d1 = 0.f, d2 = 0.f;
        {
            int i = x - 1, j = y - 1, k = z - 1;
            if ((unsigned)i < (unsigned)DIM && (unsigned)j < (unsigned)DIM &&
                (unsigned)k < (unsigned)DIM) {
                const float* b = deform + (((size_t)i * DIM + j) * DIM + k) * 3;
                d0 = b[0]; d1 = b[1]; d2 = b[2];
            }
        }
        float cx = (float)x + 0.5f + d0;
        float cy = (float)y + 0.5f + d1;
        float cz = (float)z + 0.5f + d2;

        // post-transform: (v - 1)/128 - 1 == v*(1/128) + (-(1/128) - 1)
        constexpr float S = 1.0f / 128.0f;
        constexpr float B = -(1.0f / 128.0f) - 1.0f;
        float ax = fmaf(cx - 0.3f, S, B) * m;   // OFFSET = 0.3
        float bx = fmaf(cx + 0.3f, S, B) * m;
        float ay = fmaf(cy - 0.3f, S, B) * m;
        float by = fmaf(cy + 0.3f, S, B) * m;
        float gz = fmaf(cz,        S, B) * m;

        // verts -> LDS: (ax,ay,gz)(bx,ay,gz)(bx,by,gz)(ax,by,gz)
        float4* v4 = reinterpret_cast<float4*>(sv) + t * 3;
        v4[0] = make_float4(ax, ay, gz, bx);
        v4[1] = make_float4(ay, gz, bx, by);
        v4[2] = make_float4(gz, ax, by, gz);

        // tris -> LDS: (4*cell + {0,1,2,0,2,3}) * mask  (exact in f32: < 2^24)
        float c4 = (float)(cell * 4);
        float2* t2 = reinterpret_cast<float2*>(st) + t * 3;
        t2[0] = make_float2(c4 * m,          (c4 + 1.0f) * m);
        t2[1] = make_float2((c4 + 2.0f) * m,  c4 * m);
        t2[2] = make_float2((c4 + 2.0f) * m, (c4 + 3.0f) * m);

        // vmask -> LDS
        float4* m4 = reinterpret_cast<float4*>(sm) + t;
        m4[0] = make_float4(m, m, m, m);
    }

    __syncthreads();

    // -------- coalesced copy-out: every store instruction is wave-contiguous
    const int n = min(BLK, NCELLS - c0);   // cells in this block (>=1)

    // verts: n*12 f32 = n*3 float4; global base (c0*48 B) is 16B/64B aligned
    {
        float4* gv = reinterpret_cast<float4*>(out + (size_t)c0 * 12);
        const float4* lv = reinterpret_cast<const float4*>(sv);
        for (int i = t; i < n * 3; i += BLK) gv[i] = lv[i];
    }
    // tris: n*6 f32 = n*3 float2; base NV*4 + c0*24 B is 8B aligned
    {
        float2* gt = reinterpret_cast<float2*>(out + NV_ELEMS + (size_t)c0 * 6);
        const float2* lt = reinterpret_cast<const float2*>(st);
        for (int i = t; i < n * 3; i += BLK) gt[i] = lt[i];
    }
    // vmask: n*4 f32 = n*2 float2; base is 8-mod-16 aligned -> float2
    {
        float2* gm = reinterpret_cast<float2*>(out + NV_ELEMS + NT_ELEMS + (size_t)c0 * 4);
        const float2* lm = reinterpret_cast<const float2*>(sm);
        for (int i = t; i < n * 2; i += BLK) gm[i] = lm[i];
    }
}

extern "C" void kernel_launch(void* const* d_in, const int* in_sizes, int n_in,
                              void* d_out, int out_size, void* d_ws, size_t ws_size,
                              hipStream_t stream) {
    const float* grid   = (const float*)d_in[0];   // [128,128,128] f32
    const float* deform = (const float*)d_in[1];   // [128,128,128,3] f32
    float* out = (float*)d_out;                    // [verts | tris | vmask] f32 concat

    int blocks = (NCELLS + BLK - 1) / BLK;         // 8386
    mc_kernel<<<blocks, BLK, 0, stream>>>(grid, deform, out);
}

// Round 6
// 39.704 us; speedup vs baseline: 3.0725x; 1.0030x over previous
//
#include <hip/hip_runtime.h>
#include <stdint.h>

// Problem geometry (reference: 128^3 grid, padded to 130^3, cells = 129^3)
constexpr int DIM    = 128;
constexpr int NCX    = 129;
constexpr int NCELLS = NCX * NCX * NCX;            // 2,146,689 = 8385*256 + 129
constexpr size_t NV_ELEMS = (size_t)NCELLS * 12;   // verts region: 25,760,268 f32
constexpr size_t NT_ELEMS = (size_t)NCELLS * 6;    // tris  region: 12,880,134 f32
// vmask region: NCELLS*4 f32 ; total = 47,227,158 f32 elements
// Alignments: verts base 0 (16B ok); tris base = NV*4 = 103,041,072 B (16B ok);
// vmask base = (NV+NT)*4 = 154,561,608 B (8-mod-16 -> float2 only).

constexpr int BLK = 256;

__global__ __launch_bounds__(BLK) void mc_kernel(
    const float* __restrict__ grid,
    const float* __restrict__ deform,
    float*       __restrict__ out)
{
    // LDS staging: scatter-write per cell (strides 48/24/16 B tile the 32
    // banks exactly -> conflict-free), then contiguous coalesced copy-out.
    __shared__ __align__(16) float sv[BLK * 12];   // verts  12,288 B
    __shared__ __align__(16) float st[BLK * 6];    // tris    6,144 B
    __shared__ __align__(16) float sm[BLK * 4];    // vmask   4,096 B

    const int t    = threadIdx.x;
    const int c0   = blockIdx.x * BLK;
    const int cell = c0 + t;

    if (cell < NCELLS) {
        // cell coords, z fastest (reference meshgrid 'ij' + C-order reshape)
        int z  = cell % NCX;
        int tt = cell / NCX;
        int y  = tt % NCX;
        int x  = tt / NCX;

        // 8 cube corners of padded grid; padding value 1.0 (> isovalue 0)
        float cmin = 3.4e38f, cmax = -3.4e38f;
        #pragma unroll
        for (int dx = 0; dx < 2; ++dx) {
            int i = x + dx - 1;
            bool iok = (unsigned)i < (unsigned)DIM;
            #pragma unroll
            for (int dy = 0; dy < 2; ++dy) {
                int j = y + dy - 1;
                bool jok = (unsigned)j < (unsigned)DIM;
                #pragma unroll
                for (int dz = 0; dz < 2; ++dz) {
                    int k = z + dz - 1;
                    bool kok = (unsigned)k < (unsigned)DIM;
                    float v = 1.0f;
                    if (iok && jok && kok)
                        v = grid[((size_t)i * DIM + j) * DIM + k];
                    cmin = fminf(cmin, v);
                    cmax = fmaxf(cmax, v);
                }
            }
        }
        float m = ((cmin <= 0.0f) && (cmax >= 0.0f)) ? 1.0f : 0.0f;

        // deform at padded index (x,y,z): zero in padding region
        float d0 = 0.f, d1 = 0.f, d2 = 0.f;
        {
            int i = x - 1, j = y - 1, k = z - 1;
            if ((unsigned)i < (unsigned)DIM && (unsigned)j < (unsigned)DIM &&
                (unsigned)k < (unsigned)DIM) {
                const float* b = deform + (((size_t)i * DIM + j) * DIM + k) * 3;
                d0 = b[0]; d1 = b[1]; d2 = b[2];
            }
        }
        float cx = (float)x + 0.5f + d0;
        float cy = (float)y + 0.5f + d1;
        float cz = (float)z + 0.5f + d2;

        // post-transform: (v - 1)/128 - 1 == v*(1/128) + (-(1/128) - 1)
        constexpr float S = 1.0f / 128.0f;
        constexpr float B = -(1.0f / 128.0f) - 1.0f;
        float ax = fmaf(cx - 0.3f, S, B) * m;   // OFFSET = 0.3
        float bx = fmaf(cx + 0.3f, S, B) * m;
        float ay = fmaf(cy - 0.3f, S, B) * m;
        float by = fmaf(cy + 0.3f, S, B) * m;
        float gz = fmaf(cz,        S, B) * m;

        // verts -> LDS: (ax,ay,gz)(bx,ay,gz)(bx,by,gz)(ax,by,gz)
        float4* v4 = reinterpret_cast<float4*>(sv) + t * 3;
        v4[0] = make_float4(ax, ay, gz, bx);
        v4[1] = make_float4(ay, gz, bx, by);
        v4[2] = make_float4(gz, ax, by, gz);

        // tris -> LDS: (4*cell + {0,1,2,0,2,3}) * mask  (exact in f32: < 2^24)
        float c4 = (float)(cell * 4);
        float2* t2 = reinterpret_cast<float2*>(st) + t * 3;
        t2[0] = make_float2(c4 * m,          (c4 + 1.0f) * m);
        t2[1] = make_float2((c4 + 2.0f) * m,  c4 * m);
        t2[2] = make_float2((c4 + 2.0f) * m, (c4 + 3.0f) * m);

        // vmask -> LDS
        reinterpret_cast<float4*>(sm)[t] = make_float4(m, m, m, m);
    }

    __syncthreads();

    // -------- coalesced copy-out --------
    float4*       gv  = reinterpret_cast<float4*>(out + (size_t)c0 * 12);
    const float4* lv  = reinterpret_cast<const float4*>(sv);
    float4*       gt4 = reinterpret_cast<float4*>(out + NV_ELEMS + (size_t)c0 * 6);
    const float4* lt4 = reinterpret_cast<const float4*>(st);
    float2*       gm  = reinterpret_cast<float2*>(out + NV_ELEMS + NT_ELEMS + (size_t)c0 * 4);
    const float2* lm  = reinterpret_cast<const float2*>(sm);

    if (c0 + BLK <= NCELLS) {
        // full block: compile-time trip counts, all stores wave-contiguous
        #pragma unroll
        for (int r = 0; r < 3; ++r) gv[t + r * BLK] = lv[t + r * BLK];   // 768 f4
        gt4[t] = lt4[t];                                                 // 384 f4
        if (t < BLK / 2) gt4[t + BLK] = lt4[t + BLK];
        #pragma unroll
        for (int r = 0; r < 2; ++r) gm[t + r * BLK] = lm[t + r * BLK];   // 512 f2
    } else {
        // tail block (129 cells)
        const int n = NCELLS - c0;
        for (int i = t; i < n * 3; i += BLK) gv[i] = lv[i];
        const float2* lt2 = reinterpret_cast<const float2*>(st);
        float2*       gt2 = reinterpret_cast<float2*>(out + NV_ELEMS + (size_t)c0 * 6);
        for (int i = t; i < n * 3; i += BLK) gt2[i] = lt2[i];
        for (int i = t; i < n * 2; i += BLK) gm[i] = lm[i];
    }
}

extern "C" void kernel_launch(void* const* d_in, const int* in_sizes, int n_in,
                              void* d_out, int out_size, void* d_ws, size_t ws_size,
                              hipStream_t stream) {
    const float* grid   = (const float*)d_in[0];   // [128,128,128] f32
    const float* deform = (const float*)d_in[1];   // [128,128,128,3] f32
    float* out = (float*)d_out;                    // [verts | tris | vmask] f32 concat

    int blocks = (NCELLS + BLK - 1) / BLK;         // 8386
    mc_kernel<<<blocks, BLK, 0, stream>>>(grid, deform, out);
}